// Round 2
// baseline (95.808 us; speedup 1.0000x reference)
//
#include <hip/hip_runtime.h>

// Resample 48k -> 10k: up=5, down=24, 481-tap FIR (sum-normalized, scaled by up).
// y[n] = sum_j h5[5j+r] * x[floor(24n/5)+48-j],  r=(4n)%5
// Per thread: k fixed, outputs n=5k+d (d=0..4). Window w in [0,120):
//   g = 24k-48+w,  tap index m = 24d+480-5w  (k-independent -> wave-uniform -> SGPR)
//
// LDS swizzle: pad 4 floats per 8 (m = e + (e>>3)*4).
//   - 8-chunk at e0=24*tid+8*wg -> m0 = 36*tid+12*wg : 16B-aligned, contiguous
//     -> two ds_read_b128 per chunk (30 wide reads/thread, not 120 ds_read_b32)
//   - b128 start bank-group = (9i+3wg)%8 over lane i: all 8 groups distinct
//     per 8 lanes -> conflict-free at b128 service granularity.

#define NIN   1440000
#define NOUTR 300000
#define NROWS 32
#define KTOT  60000          // outputs per row / 5
#define BK    256            // k per block
#define TILE  6240           // 24*255 + 120
#define LDSN  (TILE + (TILE/8)*4)  // 9360 floats = 36.6 KB

// T[wg*40 + d*8 + u] = 5 * h[24d + 480 - 5*(wg*8+u)]  (0 outside [0,480])
__global__ void prep_taps_kernel(const float* __restrict__ h, float* __restrict__ T) {
    int i = blockIdx.x * blockDim.x + threadIdx.x;
    if (i < 600) {
        int u  = i & 7;
        int d  = (i >> 3) % 5;
        int wg = i / 40;
        int w  = wg * 8 + u;
        int t  = 24 * d + 480 - 5 * w;
        T[i] = (t >= 0 && t <= 480) ? h[t] * 5.0f : 0.0f;
    }
}

__global__ __launch_bounds__(256) void resample_kernel(
    const float* __restrict__ x, const float* __restrict__ T, float* __restrict__ y)
{
    __shared__ float lds[LDSN];
    const int tid = threadIdx.x;
    const int k0  = blockIdx.x * BK;
    const int row = blockIdx.y;
    const float* __restrict__ xr = x + (size_t)row * NIN;
    const int g0 = 24 * k0 - 48;

    // Stage tile: float4 global loads, pad-4-per-8 swizzled LDS float4 stores.
    for (int i4 = tid; i4 < TILE / 4; i4 += 256) {
        const int e = i4 * 4;
        const int g = g0 + e;
        float4 v;
        if (g >= 0 && g + 3 < NIN) {
            v = *reinterpret_cast<const float4*>(xr + g);
        } else {
            v.x = (g + 0 >= 0 && g + 0 < NIN) ? xr[g + 0] : 0.0f;
            v.y = (g + 1 >= 0 && g + 1 < NIN) ? xr[g + 1] : 0.0f;
            v.z = (g + 2 >= 0 && g + 2 < NIN) ? xr[g + 2] : 0.0f;
            v.w = (g + 3 >= 0 && g + 3 < NIN) ? xr[g + 3] : 0.0f;
        }
        const int m = e + ((e >> 3) << 2);   // 16B-aligned, contiguous 4
        *reinterpret_cast<float4*>(&lds[m]) = v;
    }
    __syncthreads();

    float acc0 = 0.f, acc1 = 0.f, acc2 = 0.f, acc3 = 0.f, acc4 = 0.f;
    const int base = 36 * tid;               // swizzled window start (16B-aligned)
    for (int wg = 0; wg < 15; ++wg) {
        const int m0 = base + 12 * wg;
        const float4 va = *reinterpret_cast<const float4*>(&lds[m0]);
        const float4 vb = *reinterpret_cast<const float4*>(&lds[m0 + 4]);
        float xv[8] = {va.x, va.y, va.z, va.w, vb.x, vb.y, vb.z, vb.w};
        const float* __restrict__ tp = T + wg * 40;   // uniform -> s_load
        #pragma unroll
        for (int u = 0; u < 8; ++u) {
            acc0 += tp[ 0 + u] * xv[u];
            acc1 += tp[ 8 + u] * xv[u];
            acc2 += tp[16 + u] * xv[u];
            acc3 += tp[24 + u] * xv[u];
            acc4 += tp[32 + u] * xv[u];
        }
    }

    const int k = k0 + tid;
    if (k < KTOT) {
        float* __restrict__ yr = y + (size_t)row * NOUTR + (size_t)5 * k;
        yr[0] = acc0; yr[1] = acc1; yr[2] = acc2; yr[3] = acc3; yr[4] = acc4;
    }
}

extern "C" void kernel_launch(void* const* d_in, const int* in_sizes, int n_in,
                              void* d_out, int out_size, void* d_ws, size_t ws_size,
                              hipStream_t stream) {
    const float* x = (const float*)d_in[0];
    const float* h = (const float*)d_in[1];   // 481 taps
    float* y = (float*)d_out;                 // 32 x 300000 f32
    float* T = (float*)d_ws;                  // 600 floats of scratch

    prep_taps_kernel<<<3, 256, 0, stream>>>(h, T);
    dim3 grid((KTOT + BK - 1) / BK, NROWS);   // 235 x 32
    resample_kernel<<<grid, 256, 0, stream>>>(x, T, y);
}

// Round 3
// 72.467 us; speedup vs baseline: 1.3221x; 1.3221x over previous
//
#include <hip/hip_runtime.h>

// Resample 48k -> 10k: up=5, down=24, 481-tap FIR (sum-normalized, scaled by up).
// y[n] = sum_j h5[5j+r] * x[floor(24n/5)+48-j],  r=(4n)%5
// Per thread: k fixed, outputs n=5k+d (d=0..4). Window w in [0,120):
//   g = 24k-48+w,  tap index m = 24d+480-5w  (k-independent -> wave-uniform -> SGPR)
//
// LDS swizzle: pad 2 floats per 8 (m = e + (e>>3)*2), 1.25x -> 31.2 kB -> 5 blocks/CU.
//   - chunk e0=24t+8wg -> m0=30t+10wg: even (8B-aligned), 8 floats contiguous
//     -> 4x ds_read_b64 per chunk
//   - b64 bank-pair = (15*lane + c) mod 16, 15 coprime 16 -> conflict-free
// Compile-time zero-tap skip: (wg,d) group all-zero iff 24d+480-40wg < 0
//   or 24d+445-40wg > 480 (10 of 75 groups) -> ~13% fewer FMAs.

#define NIN   1440000
#define NOUTR 300000
#define NROWS 32
#define KTOT  60000          // outputs per row / 5
#define BK    256            // k per block
#define TILE  6240           // 24*255 + 120
#define LDSN  (TILE + (TILE/8)*2)  // 7800 floats = 31.2 kB

// T[wg*40 + d*8 + u] = 5 * h[24d + 480 - 5*(wg*8+u)]  (0 outside [0,480])
__global__ void prep_taps_kernel(const float* __restrict__ h, float* __restrict__ T) {
    int i = blockIdx.x * blockDim.x + threadIdx.x;
    if (i < 600) {
        int u  = i & 7;
        int d  = (i >> 3) % 5;
        int wg = i / 40;
        int w  = wg * 8 + u;
        int t  = 24 * d + 480 - 5 * w;
        T[i] = (t >= 0 && t <= 480) ? h[t] * 5.0f : 0.0f;
    }
}

__global__ __launch_bounds__(256) void resample_kernel(
    const float* __restrict__ x, const float* __restrict__ T, float* __restrict__ y)
{
    __shared__ float lds[LDSN];
    const int tid = threadIdx.x;
    const int k0  = blockIdx.x * BK;
    const int row = blockIdx.y;
    const float* __restrict__ xr = x + (size_t)row * NIN;
    const int g0 = 24 * k0 - 48;

    // Stage tile: float4 global loads, pad-2-per-8 swizzled LDS stores (2x float2).
    for (int i4 = tid; i4 < TILE / 4; i4 += 256) {
        const int e = i4 * 4;
        const int g = g0 + e;
        float4 v;
        if (g >= 0 && g + 3 < NIN) {
            v = *reinterpret_cast<const float4*>(xr + g);
        } else {
            v.x = (g + 0 >= 0 && g + 0 < NIN) ? xr[g + 0] : 0.0f;
            v.y = (g + 1 >= 0 && g + 1 < NIN) ? xr[g + 1] : 0.0f;
            v.z = (g + 2 >= 0 && g + 2 < NIN) ? xr[g + 2] : 0.0f;
            v.w = (g + 3 >= 0 && g + 3 < NIN) ? xr[g + 3] : 0.0f;
        }
        const int m = e + ((e >> 3) << 1);   // 8B-aligned, contiguous 4
        *reinterpret_cast<float2*>(&lds[m])     = make_float2(v.x, v.y);
        *reinterpret_cast<float2*>(&lds[m + 2]) = make_float2(v.z, v.w);
    }
    __syncthreads();

    float acc0 = 0.f, acc1 = 0.f, acc2 = 0.f, acc3 = 0.f, acc4 = 0.f;
    const int base = 30 * tid;               // swizzled window start (8B-aligned)
    #pragma unroll
    for (int wg = 0; wg < 15; ++wg) {
        const int m0 = base + 10 * wg;
        const float2 p0 = *reinterpret_cast<const float2*>(&lds[m0]);
        const float2 p1 = *reinterpret_cast<const float2*>(&lds[m0 + 2]);
        const float2 p2 = *reinterpret_cast<const float2*>(&lds[m0 + 4]);
        const float2 p3 = *reinterpret_cast<const float2*>(&lds[m0 + 6]);
        const float xv[8] = {p0.x, p0.y, p1.x, p1.y, p2.x, p2.y, p3.x, p3.y};
        const float* __restrict__ tp = T + wg * 40;   // uniform -> s_load
        #pragma unroll
        for (int d = 0; d < 5; ++d) {
            // compile-time skip of all-zero tap groups (wg,d both constants)
            if (24 * d + 480 - 40 * wg >= 0 && 24 * d + 445 - 40 * wg <= 480) {
                float a = (d == 0) ? acc0 : (d == 1) ? acc1 : (d == 2) ? acc2
                        : (d == 3) ? acc3 : acc4;
                #pragma unroll
                for (int u = 0; u < 8; ++u)
                    a += tp[d * 8 + u] * xv[u];
                if      (d == 0) acc0 = a;
                else if (d == 1) acc1 = a;
                else if (d == 2) acc2 = a;
                else if (d == 3) acc3 = a;
                else             acc4 = a;
            }
        }
    }

    const int k = k0 + tid;
    if (k < KTOT) {
        float* __restrict__ yr = y + (size_t)row * NOUTR + (size_t)5 * k;
        yr[0] = acc0; yr[1] = acc1; yr[2] = acc2; yr[3] = acc3; yr[4] = acc4;
    }
}

extern "C" void kernel_launch(void* const* d_in, const int* in_sizes, int n_in,
                              void* d_out, int out_size, void* d_ws, size_t ws_size,
                              hipStream_t stream) {
    const float* x = (const float*)d_in[0];
    const float* h = (const float*)d_in[1];   // 481 taps
    float* y = (float*)d_out;                 // 32 x 300000 f32
    float* T = (float*)d_ws;                  // 600 floats of scratch

    prep_taps_kernel<<<3, 256, 0, stream>>>(h, T);
    dim3 grid((KTOT + BK - 1) / BK, NROWS);   // 235 x 32
    resample_kernel<<<grid, 256, 0, stream>>>(x, T, y);
}